// Round 4
// baseline (30290.506 us; speedup 1.0000x reference)
//
#include <hip/hip_runtime.h>
#include <hip/hip_cooperative_groups.h>
#include <cmath>

namespace cg = cooperative_groups;

// Fixed problem shape: T=256, B=64, D=1024, H=1024
constexpr int TT = 256;
constexpr int BB = 64;
constexpr int DD = 1024;
constexpr int HH = 1024;
constexpr int KK = DD + HH;     // 2048
constexpr int NBLK = 256;       // 1 block/CU, 4 hidden units each
constexpr int NTHR = 512;       // 8 waves -> 2 waves/SIMD
constexpr int CK = 64;          // comb chunk (floats of K)
constexpr int NCHF = KK / CK;   // 32 chunks/step
constexpr int HPB = 4;

__device__ __forceinline__ float sigm(float v) { return 1.0f / (1.0f + expf(-v)); }

// butterfly-sum over the 4 lanes of a quad (kp bits 0,1) via DPP — all lanes
// end up holding the quad sum. 2 mov_dpp + 2 add per value.
__device__ __forceinline__ float qsum4(float x) {
  int v = __builtin_amdgcn_mov_dpp(__float_as_int(x), 0xB1, 0xF, 0xF, true); // quad_perm XOR1
  x += __int_as_float(v);
  v = __builtin_amdgcn_mov_dpp(__float_as_int(x), 0x4E, 0xF, 0xF, true);     // quad_perm XOR2
  x += __int_as_float(v);
  return x;
}

// LDS pool: 160 KiB total.
//   Wl  [16 cols][2048]  fp32  = 128 KiB   (cols = gate*4 + h_local, resident whole kernel)
//   cbA [64 rows][64 k]  fp32  =  16 KiB   (comb chunk dbuf half A; aliased by zbuf[4][64][16] in epilogue)
//   cbB [64 rows][64 k]  fp32  =  16 KiB
__global__ __launch_bounds__(NTHR, 2)
void qlstm_fused2(const float* __restrict__ x,
                  const float* __restrict__ Wf, const float* __restrict__ bf, const float* __restrict__ gbf,
                  const float* __restrict__ Wi, const float* __restrict__ bi, const float* __restrict__ gbi,
                  const float* __restrict__ Wu, const float* __restrict__ bu, const float* __restrict__ gbu,
                  const float* __restrict__ Wo, const float* __restrict__ bo, const float* __restrict__ gbo,
                  float* __restrict__ out)
{
  cg::grid_group grid = cg::this_grid();

  __shared__ float lds[40960];              // 160 KiB
  float* const Wl   = lds;                  // [16][2048]
  float* const cbA  = lds + 32768;          // [64][64]
  float* const cbB  = lds + 36864;          // [64][64]
  float* const zbuf = lds + 32768;          // alias of cbA: [4][64][16]

  const int tid  = threadIdx.x;
  const int lane = tid & 63;
  const int rg   = tid >> 6;       // wave id = row-group (8 rows each)
  const int cgp  = lane >> 4;      // 0..3 col-group (== gate)
  const int kp   = lane & 15;      // k-quad within chunk
  const int srow = tid >> 3;       // staging: row 0..63
  const int sseg = tid & 7;        // staging: float4 seg 0..7
  const int h0   = blockIdx.x * HPB;

  // ---- fill W into LDS once (each col j: gate j>>2, h_local j&3) ----
  {
    const float* Wg[4] = {Wf, Wi, Wu, Wo};
    #pragma unroll
    for (int j = 0; j < 16; ++j) {
      const float* s = Wg[j >> 2] + (size_t)(h0 + (j & 3)) * KK + tid * 4;
      const float4 w = *(const float4*)s;
      *(float4*)&Wl[j * KK + tid * 4] = w;
    }
  }

  // ---- cell-update thread state (tid<256: one (row, h_local) cell) ----
  const int urow = tid >> 2;
  const int uhl  = tid & 3;
  const int hcell = h0 + uhl;
  float bfv = 0, gbfv = 0, biv = 0, gbiv = 0, buv = 0, gbuv = 0, bov = 0, gbov = 0;
  if (tid < 256) {
    bfv = bf[hcell]; gbfv = gbf[hcell];
    biv = bi[hcell]; gbiv = gbi[hcell];
    buv = bu[hcell]; gbuv = gbu[hcell];
    bov = bo[hcell]; gbov = gbo[hcell];
  }
  float cx = 0.0f, hxl = 0.0f;

  for (int t = 0; t < TT; ++t) {
    const int nch = (t == 0) ? (DD / CK) : NCHF;   // skip hx half at t=0 (hx==0)

    float acc[8][4];
    #pragma unroll
    for (int i = 0; i < 8; ++i)
      #pragma unroll
      for (int j = 0; j < 4; ++j) acc[i][j] = 0.0f;

    // chunk loader: comb[row][k0..k0+63]; rows stride 1024 in both x and out
    auto loadChunk = [&](int kc, float4& va, float4& vb) {
      const int k0 = kc * CK;
      const float* base = (k0 < DD)
        ? (x   + (size_t)t       * BB * DD + (size_t)srow * DD + k0)
        : (out + (size_t)(t - 1) * BB * HH + (size_t)srow * HH + (k0 - DD));
      va = *(const float4*)(base + sseg * 4);
      vb = *(const float4*)(base + 32 + sseg * 4);
    };
    auto storeChunk = [&](float* cb, const float4 va, const float4 vb) {
      *(float4*)&cb[srow * CK + sseg * 4]      = va;
      *(float4*)&cb[srow * CK + 32 + sseg * 4] = vb;
    };

    // prologue: chunk0 -> cbA (safe: zbuf readers finished before grid.sync),
    // chunk1 in regs, then one barrier.
    float4 va, vb;
    loadChunk(0, va, vb);
    storeChunk(cbA, va, vb);
    loadChunk(1, va, vb);
    __syncthreads();

    // main loop: ONE barrier per chunk. write(kc+1) into the other buffer is
    // safe because readers of that buffer (chunk kc-1) finished before the
    // previous barrier; compute(kc) reads data written before that barrier.
    for (int kc = 0; kc < nch; ++kc) {
      float* const cbW = (kc & 1) ? cbA : cbB;   // receives chunk kc+1
      float* const cbR = (kc & 1) ? cbB : cbA;   // holds chunk kc
      if (kc + 1 < nch) storeChunk(cbW, va, vb);
      if (kc + 2 < nch) loadChunk(kc + 2, va, vb);

      const int cko = kc * CK;
      float4 cfr[8];
      #pragma unroll
      for (int i = 0; i < 8; ++i)
        cfr[i] = *(const float4*)&cbR[(rg * 8 + i) * CK + kp * 4];
      #pragma unroll
      for (int j = 0; j < 4; ++j) {
        const float4 w = *(const float4*)&Wl[(cgp * 4 + j) * KK + cko + kp * 4];
        #pragma unroll
        for (int i = 0; i < 8; ++i) {
          acc[i][j] = fmaf(cfr[i].x, w.x, acc[i][j]);
          acc[i][j] = fmaf(cfr[i].y, w.y, acc[i][j]);
          acc[i][j] = fmaf(cfr[i].z, w.z, acc[i][j]);
          acc[i][j] = fmaf(cfr[i].w, w.w, acc[i][j]);
        }
      }
      __syncthreads();
    }

    // reduce 16 k-parts: DPP quad-sum (16 -> 4 partials), then 4 partials via LDS
    #pragma unroll
    for (int i = 0; i < 8; ++i)
      #pragma unroll
      for (int j = 0; j < 4; ++j) acc[i][j] = qsum4(acc[i][j]);

    if ((lane & 3) == 0) {                    // one writer per quad
      const int kpg = (lane >> 2) & 3;        // which group-of-4 kp
      #pragma unroll
      for (int i = 0; i < 8; ++i) {
        const float4 v = {acc[i][0], acc[i][1], acc[i][2], acc[i][3]};
        *(float4*)&zbuf[(size_t)((kpg * 64) + rg * 8 + i) * 16 + cgp * 4] = v;
      }
    }
    __syncthreads();

    if (tid < 256) {
      float zf = bfv, zi = biv, zu = buv, zo = bov;
      #pragma unroll
      for (int p = 0; p < 4; ++p) {
        const float* zr = &zbuf[(size_t)(p * 64 + urow) * 16];
        zf += zr[0 + uhl];
        zi += zr[4 + uhl];
        zu += zr[8 + uhl];
        zo += zr[12 + uhl];
      }
      const float fg = sigm(cosf(zf) + gbfv);   // QLinearGate: cos(z)+gb
      const float ig = sigm(cosf(zi) + gbiv);
      const float gg = tanhf(cosf(zu) + gbuv);
      const float og = sigm(cosf(zo) + gbov);
      cx = fg * cx + ig * gg;
      const float hx = og * tanhf(cx);
      out[(size_t)t * BB * HH + (size_t)urow * HH + hcell] = hx;
      hxl = hx;
    }
    __threadfence();
    grid.sync();   // hx(t) visible everywhere before step t+1
  }

  if (tid < 256) {
    float* hxout = out + (size_t)TT * BB * HH;
    float* cxout = hxout + (size_t)BB * HH;
    hxout[(size_t)urow * HH + hcell] = hxl;
    cxout[(size_t)urow * HH + hcell] = cx;
  }
}

extern "C" void kernel_launch(void* const* d_in, const int* in_sizes, int n_in,
                              void* d_out, int out_size, void* d_ws, size_t ws_size,
                              hipStream_t stream) {
  const float* x   = (const float*)d_in[0];
  const float* Wf  = (const float*)d_in[1];
  const float* bf_ = (const float*)d_in[2];
  const float* gbf = (const float*)d_in[3];
  const float* Wi  = (const float*)d_in[4];
  const float* bi_ = (const float*)d_in[5];
  const float* gbi = (const float*)d_in[6];
  const float* Wu  = (const float*)d_in[7];
  const float* bu_ = (const float*)d_in[8];
  const float* gbu = (const float*)d_in[9];
  const float* Wo  = (const float*)d_in[10];
  const float* bo_ = (const float*)d_in[11];
  const float* gbo = (const float*)d_in[12];
  float* out = (float*)d_out;

  void* args[] = {&x, &Wf, &bf_, &gbf, &Wi, &bi_, &gbi, &Wu, &bu_, &gbu,
                  &Wo, &bo_, &gbo, &out};
  hipLaunchCooperativeKernel((void*)qlstm_fused2, dim3(NBLK), dim3(NTHR),
                             args, 0, stream);
}

// Round 5
// 5488.810 us; speedup vs baseline: 5.5186x; 5.5186x over previous
//
#include <hip/hip_runtime.h>
#include <cmath>
#include <cstring>

// Fixed problem shape: T=256, B=64, D=1024, H=1024
constexpr int TT = 256;
constexpr int BB = 64;
constexpr int DD = 1024;
constexpr int HH = 1024;
constexpr int KK = DD + HH;     // 2048
constexpr int NBLK = 256;       // 1 block/CU, 4 hidden units each
constexpr int NTHR = 512;       // 8 waves -> 2 waves/SIMD
constexpr int CK = 64;          // comb chunk (floats of K)
constexpr int NCHF = KK / CK;   // 32 chunks/step
constexpr int HPB = 4;

// d_ws layout (uint32): grp[(t*8+g)*16]  (8 group counters/step, 64B-padded)
//                       done[32768 + t*16]
constexpr int WS_UINTS = TT * 8 * 16 + TT * 16;   // 36864 uints = 144 KiB

__device__ __forceinline__ float sigm(float v) { return 1.0f / (1.0f + expf(-v)); }

// butterfly-sum over the 4 lanes of a quad (kp bits 0,1) via DPP
__device__ __forceinline__ float qsum4(float x) {
  int v = __builtin_amdgcn_mov_dpp(__float_as_int(x), 0xB1, 0xF, 0xF, true); // quad_perm XOR1
  x += __int_as_float(v);
  v = __builtin_amdgcn_mov_dpp(__float_as_int(x), 0x4E, 0xF, 0xF, true);     // quad_perm XOR2
  x += __int_as_float(v);
  return x;
}

// Two-level grid barrier on relaxed agent-scope atomics (no L2 wb/inv).
// Safe because ALL cross-block data (hx) moves via agent-scope (IC-coherent)
// atomics, and each wave's vmem is drained at the preceding s_barrier.
__device__ __forceinline__ void gridbar(unsigned* ws, int t, int tid, int bid) {
  __syncthreads();   // all waves arrived; each wave's hx stores drained (vmcnt0 before s_barrier)
  if (tid == 0) {
    asm volatile("s_waitcnt vmcnt(0)" ::: "memory");
    unsigned* grp  = ws + (size_t)(t * 8 + (bid >> 5)) * 16;
    unsigned* done = ws + 32768 + (size_t)t * 16;
    unsigned old = __hip_atomic_fetch_add(grp, 1u, __ATOMIC_RELAXED, __HIP_MEMORY_SCOPE_AGENT);
    if (old == 31u)
      __hip_atomic_fetch_add(done, 1u, __ATOMIC_RELAXED, __HIP_MEMORY_SCOPE_AGENT);
    while (__hip_atomic_load(done, __ATOMIC_RELAXED, __HIP_MEMORY_SCOPE_AGENT) < 8u)
      __builtin_amdgcn_s_sleep(1);
    asm volatile("" ::: "memory");   // no hx load may hoist above the poll
  }
  __syncthreads();
}

__global__ void zero_ws(unsigned* p, int n) {
  int i = blockIdx.x * blockDim.x + threadIdx.x;
  if (i < n) p[i] = 0u;
}

// LDS pool: 160 KiB.  Wl[16][2048] = 128 KiB (resident), cbA/cbB[64][64] = 16 KiB each.
// comb rows are WAVE-PRIVATE (wave rg writes+reads rows [8rg,8rg+8)) -> no barriers in chunk loop.
__global__ __launch_bounds__(NTHR, 2)
void qlstm_fused3(const float* __restrict__ x,
                  const float* __restrict__ Wf, const float* __restrict__ bf, const float* __restrict__ gbf,
                  const float* __restrict__ Wi, const float* __restrict__ bi, const float* __restrict__ gbi,
                  const float* __restrict__ Wu, const float* __restrict__ bu, const float* __restrict__ gbu,
                  const float* __restrict__ Wo, const float* __restrict__ bo, const float* __restrict__ gbo,
                  float* __restrict__ out, unsigned* __restrict__ ws)
{
  __shared__ float lds[40960];              // 160 KiB
  float* const Wl   = lds;                  // [16][2048]
  float* const cbA  = lds + 32768;          // [64][64]
  float* const cbB  = lds + 36864;          // [64][64]
  float* const zbuf = lds + 32768;          // alias of cbA: [4][64][16]

  const int tid  = threadIdx.x;
  const int lane = tid & 63;
  const int rg   = tid >> 6;       // wave id = row-group (8 rows each)
  const int cgp  = lane >> 4;      // 0..3 col-group (== gate)
  const int kp   = lane & 15;      // k-quad within chunk
  const int srow = tid >> 3;       // staging row 0..63 (== rg*8 + (lane>>3))
  const int sseg = tid & 7;        // staging float4 seg 0..7
  const int bid  = blockIdx.x;
  const int h0   = bid * HPB;

  // ---- fill W into LDS once ----
  {
    const float* Wg[4] = {Wf, Wi, Wu, Wo};
    #pragma unroll
    for (int j = 0; j < 16; ++j) {
      const float4 w = *(const float4*)(Wg[j >> 2] + (size_t)(h0 + (j & 3)) * KK + tid * 4);
      *(float4*)&Wl[j * KK + tid * 4] = w;
    }
  }

  // ---- cell-update thread state ----
  const int urow = tid >> 2;
  const int uhl  = tid & 3;
  const int hcell = h0 + uhl;
  float bfv = 0, gbfv = 0, biv = 0, gbiv = 0, buv = 0, gbuv = 0, bov = 0, gbov = 0;
  if (tid < 256) {
    bfv = bf[hcell]; gbfv = gbf[hcell];
    biv = bi[hcell]; gbiv = gbi[hcell];
    buv = bu[hcell]; gbuv = gbu[hcell];
    bov = bo[hcell]; gbov = gbo[hcell];
  }
  float cx = 0.0f, hxl = 0.0f;

  // 8B agent-scope (IC-coherent) load for hx exchange
  auto ld8 = [](const float* p) -> float2 {
    unsigned long long u = __hip_atomic_load((const unsigned long long*)(const void*)p,
                                             __ATOMIC_RELAXED, __HIP_MEMORY_SCOPE_AGENT);
    float2 r; __builtin_memcpy(&r, &u, 8); return r;
  };

  for (int t = 0; t < TT; ++t) {
    const int nch = (t == 0) ? (DD / CK) : NCHF;   // hx==0 at t=0: skip hx half

    float acc[8][4];
    #pragma unroll
    for (int i = 0; i < 8; ++i)
      #pragma unroll
      for (int j = 0; j < 4; ++j) acc[i][j] = 0.0f;

    auto loadChunk = [&](int kc, float4& va, float4& vb) {
      const int k0 = kc * CK;
      if (k0 < DD) {
        const float* base = x + (size_t)t * BB * DD + (size_t)srow * DD + k0;
        va = *(const float4*)(base + sseg * 4);
        vb = *(const float4*)(base + 32 + sseg * 4);
      } else {
        const float* base = out + (size_t)(t - 1) * BB * HH + (size_t)srow * HH + (k0 - DD);
        const float2 a0 = ld8(base + sseg * 4);
        const float2 a1 = ld8(base + sseg * 4 + 2);
        const float2 b0 = ld8(base + 32 + sseg * 4);
        const float2 b1 = ld8(base + 32 + sseg * 4 + 2);
        va = {a0.x, a0.y, a1.x, a1.y};
        vb = {b0.x, b0.y, b1.x, b1.y};
      }
    };
    auto storeChunk = [&](float* cb, const float4 va, const float4 vb) {
      *(float4*)&cb[srow * CK + sseg * 4]      = va;
      *(float4*)&cb[srow * CK + 32 + sseg * 4] = vb;
    };

    // prologue: chunk0 -> cbA, chunk1 in regs (all wave-private; no barrier)
    float4 va, vb;
    loadChunk(0, va, vb);
    storeChunk(cbA, va, vb);
    loadChunk(1, va, vb);

    for (int kc = 0; kc < nch; ++kc) {
      float* const cbW = (kc & 1) ? cbA : cbB;   // receives chunk kc+1
      float* const cbR = (kc & 1) ? cbB : cbA;   // holds chunk kc
      if (kc + 1 < nch) storeChunk(cbW, va, vb);
      if (kc + 2 < nch) loadChunk(kc + 2, va, vb);

      const int cko = kc * CK;
      float4 cfr[8];
      #pragma unroll
      for (int i = 0; i < 8; ++i)
        cfr[i] = *(const float4*)&cbR[(rg * 8 + i) * CK + kp * 4];
      #pragma unroll
      for (int j = 0; j < 4; ++j) {
        const float4 w = *(const float4*)&Wl[(cgp * 4 + j) * KK + cko + kp * 4];
        #pragma unroll
        for (int i = 0; i < 8; ++i) {
          acc[i][j] = fmaf(cfr[i].x, w.x, acc[i][j]);
          acc[i][j] = fmaf(cfr[i].y, w.y, acc[i][j]);
          acc[i][j] = fmaf(cfr[i].z, w.z, acc[i][j]);
          acc[i][j] = fmaf(cfr[i].w, w.w, acc[i][j]);
        }
      }
    }

    // k-reduce: DPP quad-sum (16 partials -> 4), then 4 via LDS
    #pragma unroll
    for (int i = 0; i < 8; ++i)
      #pragma unroll
      for (int j = 0; j < 4; ++j) acc[i][j] = qsum4(acc[i][j]);

    __syncthreads();   // all waves done reading cbA/cbB before zbuf (alias) writes
    if ((lane & 3) == 0) {
      const int kpg = (lane >> 2) & 3;
      #pragma unroll
      for (int i = 0; i < 8; ++i) {
        const float4 v = {acc[i][0], acc[i][1], acc[i][2], acc[i][3]};
        *(float4*)&zbuf[(size_t)((kpg * 64) + rg * 8 + i) * 16 + cgp * 4] = v;
      }
    }
    __syncthreads();

    if (tid < 256) {
      float zf = bfv, zi = biv, zu = buv, zo = bov;
      #pragma unroll
      for (int p = 0; p < 4; ++p) {
        const float* zr = &zbuf[(size_t)(p * 64 + urow) * 16];
        zf += zr[0 + uhl];
        zi += zr[4 + uhl];
        zu += zr[8 + uhl];
        zo += zr[12 + uhl];
      }
      const float fg = sigm(cosf(zf) + gbfv);   // QLinearGate: cos(z)+gb
      const float ig = sigm(cosf(zi) + gbiv);
      const float gg = tanhf(cosf(zu) + gbuv);
      const float og = sigm(cosf(zo) + gbov);
      cx = fg * cx + ig * gg;
      const float hx = og * tanhf(cx);
      // write-through to the coherence point: next step's cross-block reads see it
      __hip_atomic_store(&out[(size_t)t * BB * HH + (size_t)urow * HH + hcell], hx,
                         __ATOMIC_RELAXED, __HIP_MEMORY_SCOPE_AGENT);
      hxl = hx;
    }

    gridbar(ws, t, tid, bid);   // hx(t) globally visible before step t+1
  }

  if (tid < 256) {
    float* hxout = out + (size_t)TT * BB * HH;
    float* cxout = hxout + (size_t)BB * HH;
    hxout[(size_t)urow * HH + hcell] = hxl;
    cxout[(size_t)urow * HH + hcell] = cx;
  }
}

extern "C" void kernel_launch(void* const* d_in, const int* in_sizes, int n_in,
                              void* d_out, int out_size, void* d_ws, size_t ws_size,
                              hipStream_t stream) {
  const float* x   = (const float*)d_in[0];
  const float* Wf  = (const float*)d_in[1];
  const float* bf_ = (const float*)d_in[2];
  const float* gbf = (const float*)d_in[3];
  const float* Wi  = (const float*)d_in[4];
  const float* bi_ = (const float*)d_in[5];
  const float* gbi = (const float*)d_in[6];
  const float* Wu  = (const float*)d_in[7];
  const float* bu_ = (const float*)d_in[8];
  const float* gbu = (const float*)d_in[9];
  const float* Wo  = (const float*)d_in[10];
  const float* bo_ = (const float*)d_in[11];
  const float* gbo = (const float*)d_in[12];
  float* out = (float*)d_out;
  unsigned* wsp = (unsigned*)d_ws;

  // barrier counters are poisoned 0xAA before every launch -> zero them first
  zero_ws<<<(WS_UINTS + 255) / 256, 256, 0, stream>>>(wsp, WS_UINTS);

  void* args[] = {&x, &Wf, &bf_, &gbf, &Wi, &bi_, &gbi, &Wu, &bu_, &gbu,
                  &Wo, &bo_, &gbo, &out, &wsp};
  hipLaunchCooperativeKernel((void*)qlstm_fused3, dim3(NBLK), dim3(NTHR),
                             args, 0, stream);
}